// Round 1
// 2763.171 us; speedup vs baseline: 1.2541x; 1.2541x over previous
//
#include <hip/hip_runtime.h>

#define EN 262144
#define TN 2097152
#define CAP 32
#define OFCAP 262144

__device__ __forceinline__ float swishf(float x){ return x/(1.f+__expf(-x)); }

// ---------- generic tile GEMM stage (all fp32) ----------
// Block = 256 threads, tile = 64 edges x NC cols, K contraction.
// Thread t: tc = t&15 -> NC/16 cols, te = t>>4 -> 4 edges. acc in registers.
template<int K, int NC, class AF, class EP>
__device__ __forceinline__ void gemm_stage(const float* __restrict__ Wg, AF af, EP ep)
{
  constexpr int CPT = NC/16;
  const int tc = threadIdx.x & 15;
  const int te = threadIdx.x >> 4;
  const int c0 = tc*CPT;
  float acc[4][CPT];
#pragma unroll
  for(int i=0;i<4;i++)
#pragma unroll
    for(int j=0;j<CPT;j++) acc[i][j]=0.f;

  for (int k=0;k<K;k+=4){
    float a[4][4];
#pragma unroll
    for(int i=0;i<4;i++){
      float4 t = af(te*4+i, k);
      a[i][0]=t.x; a[i][1]=t.y; a[i][2]=t.z; a[i][3]=t.w;
    }
#pragma unroll
    for(int kk=0;kk<4;kk++){
      float w[CPT];
      const float* wp = Wg + (size_t)(k+kk)*NC + c0;
      float4 w0 = *(const float4*)wp;
      w[0]=w0.x; w[1]=w0.y; w[2]=w0.z; w[3]=w0.w;
      if constexpr (CPT==8){
        float4 w1 = *(const float4*)(wp+4);
        w[4]=w1.x; w[5]=w1.y; w[6]=w1.z; w[7]=w1.w;
      }
#pragma unroll
      for(int i=0;i<4;i++)
#pragma unroll
        for(int j=0;j<CPT;j++)
          acc[i][j] = fmaf(a[i][kk], w[j], acc[i][j]);
    }
  }
  ep(acc, te, c0);
}

// ---------- k0: fold basis projections ----------
__global__ void k0_prebasis(const float* __restrict__ Ws1, const float* __restrict__ Ws2,
                            const float* __restrict__ Wr1, const float* __restrict__ Wr2,
                            float* __restrict__ Psbf, float* __restrict__ Prbf)
{
  int idx = blockIdx.x*256 + threadIdx.x;
  if (idx < 42*64){
    int r = idx>>6, a = idx&63;
    float s=0.f;
#pragma unroll
    for(int j=0;j<8;j++) s = fmaf(Ws1[r*8+j], Ws2[j*64+a], s);
    Psbf[idx]=s;
  }
  if (idx < 6*128){
    int r = idx>>7, c = idx&127;
    float s=0.f;
#pragma unroll
    for(int j=0;j<8;j++) s = fmaf(Wr1[r*8+j], Wr2[j*128+c], s);
    Prbf[idx]=s;
  }
}

// ---------- k1: m_ang2 = swish( (swish(m_input@W_kj+b_kj) * rbf_p) @ W_down ) ----------
__global__ __launch_bounds__(256) void k1_pre(
  const float* __restrict__ mi, const float* __restrict__ rbf,
  const float* __restrict__ Wkj, const float* __restrict__ bkj,
  const float* __restrict__ Wdown, const float* __restrict__ Prbf,
  float* __restrict__ mang2)
{
  __shared__ __align__(16) float hs[64*128];
  const int eb = blockIdx.x*64;

  auto afG = [&](int e,int k)->float4{
    return *(const float4*)(mi + (size_t)(eb+e)*128 + k);
  };
  gemm_stage<128,128>(Wkj, afG, [&](float (&acc)[4][8], int te, int c0){
    float bb[8];
#pragma unroll
    for(int j=0;j<8;j++) bb[j]=bkj[c0+j];
#pragma unroll
    for(int i=0;i<4;i++){
      int e = te*4+i;
      size_t ge = (size_t)(eb+e);
      float rp[8];
#pragma unroll
      for(int j=0;j<8;j++) rp[j]=0.f;
#pragma unroll
      for(int r=0;r<6;r++){
        float rv = rbf[ge*6+r];
        const float* prow = Prbf + r*128 + c0;
        float4 p0 = *(const float4*)prow;
        float4 p1 = *(const float4*)(prow+4);
        rp[0]=fmaf(rv,p0.x,rp[0]); rp[1]=fmaf(rv,p0.y,rp[1]);
        rp[2]=fmaf(rv,p0.z,rp[2]); rp[3]=fmaf(rv,p0.w,rp[3]);
        rp[4]=fmaf(rv,p1.x,rp[4]); rp[5]=fmaf(rv,p1.y,rp[5]);
        rp[6]=fmaf(rv,p1.z,rp[6]); rp[7]=fmaf(rv,p1.w,rp[7]);
      }
#pragma unroll
      for(int j=0;j<8;j++)
        hs[e*128+c0+j] = swishf(acc[i][j]+bb[j])*rp[j];
    }
  });
  __syncthreads();
  auto afL = [&](int e,int k)->float4{ return *(const float4*)(hs + e*128 + k); };
  gemm_stage<128,64>(Wdown, afL, [&](float (&acc)[4][4], int te, int c0){
#pragma unroll
    for(int i=0;i<4;i++){
      size_t ge = (size_t)(eb + te*4+i);
      float4 v = make_float4(swishf(acc[i][0]),swishf(acc[i][1]),
                             swishf(acc[i][2]),swishf(acc[i][3]));
      *(float4*)(mang2 + ge*64 + c0) = v;
    }
  });
}

// ---------- ka: bin triplets by destination edge (capacity CAP + overflow list) ----------
__global__ __launch_bounds__(256) void ka_bin(
  const int* __restrict__ rji,
  int* __restrict__ cnt, int* __restrict__ perm,
  int* __restrict__ ofcnt, int* __restrict__ oflist)
{
  size_t t = (size_t)blockIdx.x*256 + threadIdx.x;
  int ji = rji[t];
  int slot = atomicAdd(cnt + ji, 1);
  if (slot < CAP) {
    perm[(size_t)ji*CAP + slot] = (int)t;
  } else {
    int o = atomicAdd(ofcnt, 1);
    if (o < OFCAP) oflist[o] = (int)t;
  }
}

// ---------- k2: gather-side reduction. One wave per edge (grid-stride),
// Psbf column register-resident, sbf row on the scalar path, ONE plain
// 256B store per edge (no atomics). ----------
__global__ __launch_bounds__(256) void k2_gather(
  const float* __restrict__ sbf, const int* __restrict__ ekj,
  const int* __restrict__ cnt, const int* __restrict__ perm,
  const float* __restrict__ Psbf, const float* __restrict__ mang2,
  float* __restrict__ agg)
{
  const int lane = threadIdx.x & 63;
  const int wid  = blockIdx.x*4 + (threadIdx.x >> 6);
  const int nw   = gridDim.x*4;

  // Psbf column for this lane, loaded once per (long-lived) wave
  float P[42];
#pragma unroll
  for (int r=0;r<42;r++) P[r] = Psbf[r*64 + lane];

  for (int e = wid; e < EN; e += nw) {
    int n = cnt[e]; if (n > CAP) n = CAP;
    const int* pl = perm + (size_t)e*CAP;
    float acc = 0.f;
    for (int i=0;i<n;i++) {
      int t  = __builtin_amdgcn_readfirstlane(pl[i]);
      int kj = __builtin_amdgcn_readfirstlane(ekj[t]);
      float mv = mang2[(size_t)kj*64 + lane];      // issue gather early
      const float* su = sbf + (size_t)t*42;        // uniform -> scalar loads
      float sp0 = 0.f, sp1 = 0.f;
#pragma unroll
      for (int r=0;r<42;r+=2){
        sp0 = fmaf(su[r],   P[r],   sp0);
        sp1 = fmaf(su[r+1], P[r+1], sp1);
      }
      acc = fmaf(mv, sp0 + sp1, acc);
    }
    agg[(size_t)e*64 + lane] = acc;
  }
}

// ---------- kof: the rare overflow triplets via the old atomic path ----------
__global__ __launch_bounds__(256) void kof(
  const int* __restrict__ ofcnt, const int* __restrict__ oflist,
  const float* __restrict__ sbf, const int* __restrict__ rji,
  const int* __restrict__ ekj, const float* __restrict__ Psbf,
  const float* __restrict__ mang2, float* __restrict__ agg)
{
  int n = *ofcnt; if (n > OFCAP) n = OFCAP;
  const int lane = threadIdx.x & 63;
  for (int i = blockIdx.x*4 + (threadIdx.x>>6); i < n; i += gridDim.x*4) {
    int t = oflist[i];
    const float* su = sbf + (size_t)t*42;
    float sp = 0.f;
#pragma unroll
    for (int r=0;r<42;r++) sp = fmaf(su[r], Psbf[r*64+lane], sp);
    float val = mang2[(size_t)ekj[t]*64 + lane] * sp;
    atomicAdd(agg + (size_t)rji[t]*64 + lane, val);
  }
}

// ---------- k3: edge epilogue chain (9 GEMM stages, LDS ping-pong) ----------
__global__ __launch_bounds__(256) void k3_post(
  const float* __restrict__ mi, const float* __restrict__ agg,
  const float* __restrict__ Wup, const float* __restrict__ Wji, const float* __restrict__ bji,
  const float* __restrict__ Wrb, const float* __restrict__ brb,
  const float* __restrict__ Wfin, const float* __restrict__ bfin,
  const float* __restrict__ Wra, const float* __restrict__ bra,
  float* __restrict__ outp)
{
  __shared__ __align__(16) float xs[64*128];
  __shared__ __align__(16) float hs[64*128];
  const int eb = blockIdx.x*64;

  auto afA = [&](int e,int k)->float4{ return *(const float4*)(agg + (size_t)(eb+e)*64 + k); };
  auto afG = [&](int e,int k)->float4{ return *(const float4*)(mi + (size_t)(eb+e)*128 + k); };
  auto afX = [&](int e,int k)->float4{ return *(const float4*)(xs + e*128 + k); };
  auto afH = [&](int e,int k)->float4{ return *(const float4*)(hs + e*128 + k); };

  // S1: x = swish(agg @ W_up)           (prop)
  gemm_stage<64,128>(Wup, afA, [&](float (&acc)[4][8], int te, int c0){
#pragma unroll
    for(int i=0;i<4;i++){ int e=te*4+i;
#pragma unroll
      for(int j=0;j<8;j++) xs[e*128+c0+j] = swishf(acc[i][j]);
    }
  });
  // S2: x += swish(m_input @ W_ji + b_ji)  (same thread owns same elems as S1)
  gemm_stage<128,128>(Wji, afG, [&](float (&acc)[4][8], int te, int c0){
    float bb[8];
#pragma unroll
    for(int j=0;j<8;j++) bb[j]=bji[c0+j];
#pragma unroll
    for(int i=0;i<4;i++){ int e=te*4+i;
#pragma unroll
      for(int j=0;j<8;j++) xs[e*128+c0+j] += swishf(acc[i][j]+bb[j]);
    }
  });
  __syncthreads();
  // S3: h = swish(x @ Wrb0 + brb0)
  gemm_stage<128,128>(Wrb, afX, [&](float (&acc)[4][8], int te, int c0){
    float bb[8];
#pragma unroll
    for(int j=0;j<8;j++) bb[j]=brb[c0+j];
#pragma unroll
    for(int i=0;i<4;i++){ int e=te*4+i;
#pragma unroll
      for(int j=0;j<8;j++) hs[e*128+c0+j] = swishf(acc[i][j]+bb[j]);
    }
  });
  __syncthreads();
  // S4: x += swish(h @ Wrb1 + brb1)     (residual skip)
  gemm_stage<128,128>(Wrb+16384, afH, [&](float (&acc)[4][8], int te, int c0){
    float bb[8];
#pragma unroll
    for(int j=0;j<8;j++) bb[j]=brb[128+c0+j];
#pragma unroll
    for(int i=0;i<4;i++){ int e=te*4+i;
#pragma unroll
      for(int j=0;j<8;j++) xs[e*128+c0+j] += swishf(acc[i][j]+bb[j]);
    }
  });
  __syncthreads();
  // S5: h = swish(x @ W_final + b_final) + m_input
  gemm_stage<128,128>(Wfin, afX, [&](float (&acc)[4][8], int te, int c0){
    float bb[8];
#pragma unroll
    for(int j=0;j<8;j++) bb[j]=bfin[c0+j];
#pragma unroll
    for(int i=0;i<4;i++){ int e=te*4+i;
      const float* p = mi + (size_t)(eb+e)*128 + c0;
      float4 m0 = *(const float4*)p;
      float4 m1 = *(const float4*)(p+4);
      float m[8] = {m0.x,m0.y,m0.z,m0.w,m1.x,m1.y,m1.z,m1.w};
#pragma unroll
      for(int j=0;j<8;j++) hs[e*128+c0+j] = swishf(acc[i][j]+bb[j]) + m[j];
    }
  });
  __syncthreads();
  // S6: x = swish(h @ Wra00 + bra00)
  gemm_stage<128,128>(Wra, afH, [&](float (&acc)[4][8], int te, int c0){
    float bb[8];
#pragma unroll
    for(int j=0;j<8;j++) bb[j]=bra[c0+j];
#pragma unroll
    for(int i=0;i<4;i++){ int e=te*4+i;
#pragma unroll
      for(int j=0;j<8;j++) xs[e*128+c0+j] = swishf(acc[i][j]+bb[j]);
    }
  });
  __syncthreads();
  // S7: h += swish(x @ Wra01 + bra01)
  gemm_stage<128,128>(Wra+16384, afX, [&](float (&acc)[4][8], int te, int c0){
    float bb[8];
#pragma unroll
    for(int j=0;j<8;j++) bb[j]=bra[128+c0+j];
#pragma unroll
    for(int i=0;i<4;i++){ int e=te*4+i;
#pragma unroll
      for(int j=0;j<8;j++) hs[e*128+c0+j] += swishf(acc[i][j]+bb[j]);
    }
  });
  __syncthreads();
  // S8: x = swish(h @ Wra10 + bra10)
  gemm_stage<128,128>(Wra+32768, afH, [&](float (&acc)[4][8], int te, int c0){
    float bb[8];
#pragma unroll
    for(int j=0;j<8;j++) bb[j]=bra[256+c0+j];
#pragma unroll
    for(int i=0;i<4;i++){ int e=te*4+i;
#pragma unroll
      for(int j=0;j<8;j++) xs[e*128+c0+j] = swishf(acc[i][j]+bb[j]);
    }
  });
  __syncthreads();
  // S9: out = h + swish(x @ Wra11 + bra11)
  gemm_stage<128,128>(Wra+49152, afX, [&](float (&acc)[4][8], int te, int c0){
    float bb[8];
#pragma unroll
    for(int j=0;j<8;j++) bb[j]=bra[384+c0+j];
#pragma unroll
    for(int i=0;i<4;i++){ int e=te*4+i;
      size_t ge = (size_t)(eb+e);
      float o[8];
#pragma unroll
      for(int j=0;j<8;j++) o[j] = hs[e*128+c0+j] + swishf(acc[i][j]+bb[j]);
      *(float4*)(outp + ge*128 + c0)   = make_float4(o[0],o[1],o[2],o[3]);
      *(float4*)(outp + ge*128 + c0+4) = make_float4(o[4],o[5],o[6],o[7]);
    }
  });
}

extern "C" void kernel_launch(void* const* d_in, const int* in_sizes, int n_in,
                              void* d_out, int out_size, void* d_ws, size_t ws_size,
                              hipStream_t stream)
{
  (void)in_sizes; (void)n_in; (void)out_size; (void)ws_size;
  const float* mi   = (const float*)d_in[0];
  const float* rbf  = (const float*)d_in[1];
  const float* sbf  = (const float*)d_in[2];
  const int*   rji  = (const int*)d_in[3];
  const int*   ekj  = (const int*)d_in[4];
  const float* Wkj  = (const float*)d_in[5];
  const float* bkj  = (const float*)d_in[6];
  const float* Wr1  = (const float*)d_in[7];
  const float* Wr2  = (const float*)d_in[8];
  const float* Ws1  = (const float*)d_in[9];
  const float* Ws2  = (const float*)d_in[10];
  const float* Wdn  = (const float*)d_in[11];
  const float* Wup  = (const float*)d_in[12];
  const float* Wji  = (const float*)d_in[13];
  const float* bji  = (const float*)d_in[14];
  const float* Wrb  = (const float*)d_in[15];
  const float* brb  = (const float*)d_in[16];
  const float* Wfin = (const float*)d_in[17];
  const float* bfin = (const float*)d_in[18];
  const float* Wra  = (const float*)d_in[19];
  const float* bra  = (const float*)d_in[20];

  char* ws = (char*)d_ws;
  float* mang2 = (float*)ws;                                   // E*64 f32 = 64 MB
  float* agg   = (float*)(ws + (size_t)EN*64*4);               // E*64 f32 = 64 MB
  float* Psbf  = (float*)(ws + (size_t)EN*64*8);               // 42*64 f32
  float* Prbf  = Psbf + 42*64;                                 // 6*128 f32
  int*   cnt   = (int*)(ws + (size_t)EN*64*8 + 65536);         // E i32 = 1 MB
  int*   ofcnt = cnt + EN;                                     // 1 i32
  int*   perm  = (int*)((char*)cnt + (size_t)EN*4 + 256);      // E*CAP i32 = 32 MB
  int*   oflist= perm + (size_t)EN*CAP;                        // OFCAP i32 = 1 MB

  // zero bin counters (+ overflow counter); agg memset no longer needed
  hipMemsetAsync(cnt, 0, (size_t)EN*4 + 256, stream);
  k0_prebasis<<<11, 256, 0, stream>>>(Ws1, Ws2, Wr1, Wr2, Psbf, Prbf);
  ka_bin<<<TN/256, 256, 0, stream>>>(rji, cnt, perm, ofcnt, oflist);
  k1_pre<<<EN/64, 256, 0, stream>>>(mi, rbf, Wkj, bkj, Wdn, Prbf, mang2);
  k2_gather<<<2048, 256, 0, stream>>>(sbf, ekj, cnt, perm, Psbf, mang2, agg);
  kof<<<64, 256, 0, stream>>>(ofcnt, oflist, sbf, rji, ekj, Psbf, mang2, agg);
  k3_post<<<EN/64, 256, 0, stream>>>(mi, agg, Wup, Wji, bji, Wrb, brb,
                                     Wfin, bfin, Wra, bra, (float*)d_out);
}